// Round 1
// baseline (495.137 us; speedup 1.0000x reference)
//
#include <hip/hip_runtime.h>
#include <hip/hip_bf16.h>
#include <cstdint>
#include <cstddef>

#define BATCH 4
#define SEQ   4096
#define EMB   1024
#define NH    16
#define HD    64
#define M_TOT (BATCH * SEQ)   // 16384
#define KV_CHUNKS 16

using bf16_t = __hip_bfloat16;
typedef __attribute__((ext_vector_type(8))) short bv8;    // 8 bf16 (4 VGPRs)
typedef __attribute__((ext_vector_type(4))) float f32x4;

union SV8 { bv8 v; bf16_t h[8]; };

__device__ __forceinline__ void gload_lds16(const void* g, void* l) {
  __builtin_amdgcn_global_load_lds(
      (const __attribute__((address_space(1))) unsigned int*)g,
      (__attribute__((address_space(3))) unsigned int*)l, 16, 0, 0);
}

// ---------- fp32 -> bf16 convert (exact grids; 8 elems/thread) ----------
__global__ __launch_bounds__(256) void cvt_kernel(const float* __restrict__ in,
                                                  bf16_t* __restrict__ out) {
  const size_t i = ((size_t)blockIdx.x * 256 + threadIdx.x) * 8;
  const f32x4 a = *(const f32x4*)(in + i);
  const f32x4 b = *(const f32x4*)(in + i + 4);
  SV8 o;
#pragma unroll
  for (int j = 0; j < 4; ++j) o.h[j] = __float2bfloat16(a[j]);
#pragma unroll
  for (int j = 0; j < 4; ++j) o.h[4 + j] = __float2bfloat16(b[j]);
  *(bv8*)(out + i) = o.v;
}

// ---------- C = A @ W^T (+bias, +optional elu+1) ----------
// A: [16384, 1024] bf16 row-major. W: [1024, 1024] bf16 row-major (torch Linear).
// MODE 0: elu(x)+1 -> bf16 out; MODE 1: identity -> bf16 out; MODE 2: identity -> fp32 out.
// 128x128 tile, BK=32, 4 waves each computing 64x64. LDS in "fragment order":
// byte offset = mb*1024 + ks*256 + r*16 holds A[mb*16+r][ks*8 .. +7]; a wave's
// ds_read_b128 at base + lane*16 is a contiguous conflict-free 1KB block, and the
// global_load_lds destination (wave-uniform base + lane*16) matches it exactly.
template <int MODE>
__global__ __launch_bounds__(256, 3) void gemm_bt(
    const bf16_t* __restrict__ A, const bf16_t* __restrict__ W,
    const float* __restrict__ bias, void* __restrict__ Cout) {
  constexpr int K = EMB;   // 1024
  constexpr int N = EMB;   // 1024
  __shared__ bf16_t Al[128 * 32];
  __shared__ bf16_t Bl[128 * 32];

  const int nwg = gridDim.x;                       // 1024, %8 == 0
  const int wg = (blockIdx.x % 8) * (nwg >> 3) + (blockIdx.x >> 3);  // XCD swizzle
  const int NT = N / 128;                          // 8
  const int m0 = (wg / NT) * 128;
  const int n0 = (wg % NT) * 128;
  const int t = threadIdx.x, l = t & 63, w = t >> 6;
  const int wm = (w >> 1) * 64, wn = (w & 1) * 64;

  f32x4 acc[4][4] = {};
  const int abase = (wm >> 4) * 1024 + l * 16;     // LDS byte offsets
  const int bbase = (wn >> 4) * 1024 + l * 16;

  for (int kt = 0; kt < K / 32; ++kt) {
    const int k0 = kt * 32;
#pragma unroll
    for (int j = 0; j < 2; ++j) {
      const int vt = j * 256 + t;
      const int row = ((vt >> 6) << 4) + (vt & 15);
      const int col = ((vt >> 4) & 3) << 3;
      gload_lds16(A + (size_t)(m0 + row) * K + (k0 + col), (char*)Al + vt * 16);
      gload_lds16(W + (size_t)(n0 + row) * K + (k0 + col), (char*)Bl + vt * 16);
    }
    __syncthreads();   // compiler emits s_waitcnt vmcnt(0) before the barrier
    bv8 af[4], bfr[4];
#pragma unroll
    for (int i = 0; i < 4; ++i)
      af[i] = *(const bv8*)((const char*)Al + abase + i * 1024);
#pragma unroll
    for (int j = 0; j < 4; ++j)
      bfr[j] = *(const bv8*)((const char*)Bl + bbase + j * 1024);
#pragma unroll
    for (int i = 0; i < 4; ++i)
#pragma unroll
      for (int j = 0; j < 4; ++j)
        acc[i][j] = __builtin_amdgcn_mfma_f32_16x16x32_bf16(af[i], bfr[j],
                                                            acc[i][j], 0, 0, 0);
    __syncthreads();
  }

  // C/D: col = lane&15, row = (lane>>4)*4 + reg  [m89/m91-verified]
  const int cr = (l >> 4) << 2, cc = l & 15;
#pragma unroll
  for (int j = 0; j < 4; ++j) {
    const int gcol = n0 + wn + j * 16 + cc;
    const float bz = bias[gcol];
#pragma unroll
    for (int i = 0; i < 4; ++i) {
      const int grow = m0 + wm + i * 16 + cr;
#pragma unroll
      for (int r = 0; r < 4; ++r) {
        float v = acc[i][j][r] + bz;
        if (MODE == 0) v = (v > 0.f) ? (v + 1.f) : __expf(v);  // elu(x)+1
        if (MODE == 2)
          ((float*)Cout)[(size_t)(grow + r) * N + gcol] = v;
        else
          ((bf16_t*)Cout)[(size_t)(grow + r) * N + gcol] = __float2bfloat16(v);
      }
    }
  }
}

// ---------- kv partial: pkv[chunk][bh][d][e] = sum_{s in chunk} k[s,d]*v[s,e] ----------
__global__ __launch_bounds__(256) void kv_partial(const bf16_t* __restrict__ Kmat,
                                                  const bf16_t* __restrict__ Vmat,
                                                  float* __restrict__ pkv) {
  const int chunk = blockIdx.x;   // 0..15
  const int bh = blockIdx.y;      // 0..63
  const int b = bh >> 4, h = bh & 15;
  const int t = threadIdx.x;
  __shared__ bf16_t kl[8][64], vl[8][64];
  float acc[16] = {};
  const int e = t & 63, d0 = (t >> 6) * 16;
  const int sl = t >> 5, c2 = (t & 31) * 2;
  const int s0 = chunk * (SEQ / KV_CHUNKS);
  const bf16_t* kp = Kmat + ((size_t)(b * SEQ + s0 + sl)) * EMB + h * 64 + c2;
  const bf16_t* vp = Vmat + ((size_t)(b * SEQ + s0 + sl)) * EMB + h * 64 + c2;
  for (int it = 0; it < (SEQ / KV_CHUNKS) / 8; ++it) {  // 32 iters of 8 rows
    const unsigned int kw = *(const unsigned int*)kp;
    const unsigned int vw = *(const unsigned int*)vp;
    __syncthreads();
    *(unsigned int*)&kl[sl][c2] = kw;
    *(unsigned int*)&vl[sl][c2] = vw;
    __syncthreads();
#pragma unroll
    for (int ss = 0; ss < 8; ++ss) {
      const float vv = __bfloat162float(vl[ss][e]);   // 64-lane 2B stride-1: free
      SV8 k0, k1;
      k0.v = *(const bv8*)&kl[ss][d0];                // wave-broadcast reads
      k1.v = *(const bv8*)&kl[ss][d0 + 8];
#pragma unroll
      for (int dd = 0; dd < 8; ++dd) acc[dd] += __bfloat162float(k0.h[dd]) * vv;
#pragma unroll
      for (int dd = 0; dd < 8; ++dd) acc[8 + dd] += __bfloat162float(k1.h[dd]) * vv;
    }
    kp += 8 * EMB;
    vp += 8 * EMB;
  }
  float* outp = pkv + ((size_t)chunk * 64 + bh) * 4096;
#pragma unroll
  for (int dd = 0; dd < 16; ++dd) outp[(d0 + dd) * 64 + e] = acc[dd];
}

// ---------- kv reduce over chunks + transpose -> kvT[bh][e][d] (bf16) ----------
__global__ __launch_bounds__(256) void kv_reduce(const float* __restrict__ pkv,
                                                 bf16_t* __restrict__ kvT) {
  const int bh = blockIdx.x;
  const int t = threadIdx.x;
  __shared__ float tile[64][65];   // +1 pad: conflict-free transposed reads
#pragma unroll
  for (int ii = 0; ii < 16; ++ii) {
    const int idx = ii * 256 + t;  // d*64 + e
    float s = 0.f;
#pragma unroll
    for (int c = 0; c < KV_CHUNKS; ++c)
      s += pkv[((size_t)c * 64 + bh) * 4096 + idx];
    tile[idx >> 6][idx & 63] = s;
  }
  __syncthreads();
  bf16_t* outp = kvT + (size_t)bh * 4096;
#pragma unroll
  for (int ii = 0; ii < 16; ++ii) {
    const int o = ii * 256 + t;    // e*64 + d
    outp[o] = __float2bfloat16(tile[o & 63][o >> 6]);
  }
}

// ---------- ctx[s, h*64+e] = sum_d q[s, h*64+d] * kvT[bh][e][d]  (MFMA) ----------
__global__ __launch_bounds__(256, 4) void qkv_apply(const bf16_t* __restrict__ Q,
                                                    const bf16_t* __restrict__ kvT,
                                                    bf16_t* __restrict__ ctx) {
  __shared__ bf16_t Ql[128 * 64];  // frag order, fb = mb*2 + kt
  __shared__ bf16_t Bl[64 * 64];
  const int st = blockIdx.x;       // 0..31 (s-tile of 128)
  const int bh = blockIdx.y;       // 0..63
  const int b = bh >> 4, h = bh & 15;
  const int t = threadIdx.x, l = t & 63, w = t >> 6;

  const size_t qbase = ((size_t)(b * SEQ + st * 128)) * EMB + h * 64;
#pragma unroll
  for (int j = 0; j < 4; ++j) {
    const int vt = j * 256 + t;
    const int fb = vt >> 6;
    const int row = (fb >> 1) * 16 + (vt & 15);
    const int col = (fb & 1) * 32 + (((vt >> 4) & 3) << 3);
    gload_lds16(Q + qbase + (size_t)row * EMB + col, (char*)Ql + vt * 16);
  }
  const bf16_t* kvb = kvT + (size_t)bh * 4096;  // [64 e][64 d] row-major
#pragma unroll
  for (int j = 0; j < 2; ++j) {
    const int vt = j * 256 + t;
    const int fb = vt >> 6;
    const int row = (fb >> 1) * 16 + (vt & 15);
    const int col = (fb & 1) * 32 + (((vt >> 4) & 3) << 3);
    gload_lds16(kvb + row * 64 + col, (char*)Bl + vt * 16);
  }
  __syncthreads();

  f32x4 acc[2][4] = {};
#pragma unroll
  for (int kt = 0; kt < 2; ++kt) {
    bv8 a[2], bb[4];
#pragma unroll
    for (int i = 0; i < 2; ++i)
      a[i] = *(const bv8*)((const char*)Ql + (((w * 2 + i) * 2 + kt) * 1024) + l * 16);
#pragma unroll
    for (int j = 0; j < 4; ++j)
      bb[j] = *(const bv8*)((const char*)Bl + ((j * 2 + kt) * 1024) + l * 16);
#pragma unroll
    for (int i = 0; i < 2; ++i)
#pragma unroll
      for (int j = 0; j < 4; ++j)
        acc[i][j] = __builtin_amdgcn_mfma_f32_16x16x32_bf16(a[i], bb[j],
                                                            acc[i][j], 0, 0, 0);
  }

  const int cr = (l >> 4) << 2, cc = l & 15;
#pragma unroll
  for (int i = 0; i < 2; ++i)
#pragma unroll
    for (int j = 0; j < 4; ++j)
#pragma unroll
      for (int r = 0; r < 4; ++r) {
        const int row = st * 128 + w * 32 + i * 16 + cr + r;
        ctx[((size_t)(b * SEQ + row)) * EMB + h * 64 + j * 16 + cc] =
            __float2bfloat16(acc[i][j][r]);
      }
}

extern "C" void kernel_launch(void* const* d_in, const int* in_sizes, int n_in,
                              void* d_out, int out_size, void* d_ws, size_t ws_size,
                              hipStream_t stream) {
  (void)in_sizes; (void)n_in; (void)out_size;
  const float* x  = (const float*)d_in[0];
  const float* Wq = (const float*)d_in[1];
  const float* bq = (const float*)d_in[2];
  const float* Wk = (const float*)d_in[3];
  const float* bk = (const float*)d_in[4];
  const float* Wv = (const float*)d_in[5];
  const float* bv = (const float*)d_in[6];
  const float* Wo = (const float*)d_in[7];
  const float* bo = (const float*)d_in[8];

  // Workspace carve-up (~88.5 MB):
  //   xb 32MB | Wq/Wk/Wv/Wo bf16 2MB each | vb 32MB | pkv 16MB | kvT 0.5MB
  // ctx aliases xb (x dead after projections). q,k live in d_out (64MB),
  // both dead before the final projection overwrites d_out.
  const size_t NEED = 33554432ull + 4ull * 2097152ull + 33554432ull +
                      16777216ull + 524288ull;
  if (ws_size < NEED) return;  // defined failure instead of corruption

  char* p = (char*)d_ws;
  bf16_t* xb  = (bf16_t*)p;
  bf16_t* wqb = (bf16_t*)(p + 33554432ull);
  bf16_t* wkb = (bf16_t*)(p + 33554432ull + 2097152ull);
  bf16_t* wvb = (bf16_t*)(p + 33554432ull + 2ull * 2097152ull);
  bf16_t* wob = (bf16_t*)(p + 33554432ull + 3ull * 2097152ull);
  bf16_t* vbuf = (bf16_t*)(p + 33554432ull + 4ull * 2097152ull);
  float*  pkv = (float*)(p + 2ull * 33554432ull + 4ull * 2097152ull);
  bf16_t* kvT = (bf16_t*)(p + 2ull * 33554432ull + 4ull * 2097152ull + 16777216ull);
  bf16_t* ctx = xb;

  bf16_t* qb = (bf16_t*)d_out;
  bf16_t* kb = qb + (size_t)M_TOT * EMB;

  cvt_kernel<<<8192, 256, 0, stream>>>(x, xb);    // 16.7M elems
  cvt_kernel<<<512, 256, 0, stream>>>(Wq, wqb);   // 1M elems each
  cvt_kernel<<<512, 256, 0, stream>>>(Wk, wkb);
  cvt_kernel<<<512, 256, 0, stream>>>(Wv, wvb);
  cvt_kernel<<<512, 256, 0, stream>>>(Wo, wob);

  gemm_bt<0><<<1024, 256, 0, stream>>>(xb, wqb, bq, qb);    // q = elu+1
  gemm_bt<0><<<1024, 256, 0, stream>>>(xb, wkb, bk, kb);    // k = elu+1
  gemm_bt<1><<<1024, 256, 0, stream>>>(xb, wvb, bv, vbuf);  // v

  kv_partial<<<dim3(KV_CHUNKS, 64), 256, 0, stream>>>(kb, vbuf, pkv);
  kv_reduce<<<64, 256, 0, stream>>>(pkv, kvT);

  qkv_apply<<<dim3(32, 64), 256, 0, stream>>>(qb, kvT, ctx);

  gemm_bt<2><<<1024, 256, 0, stream>>>(ctx, wob, bo, d_out);  // final fp32 out
}

// Round 2
// 408.819 us; speedup vs baseline: 1.2111x; 1.2111x over previous
//
#include <hip/hip_runtime.h>
#include <hip/hip_bf16.h>
#include <cstdint>
#include <cstddef>

#define BATCH 4
#define SEQ   4096
#define EMB   1024
#define NH    16
#define HD    64
#define M_TOT (BATCH * SEQ)   // 16384
#define KV_CHUNKS 16

using bf16_t = __hip_bfloat16;
typedef __attribute__((ext_vector_type(8))) short bv8;    // 8 bf16 (4 VGPRs)
typedef __attribute__((ext_vector_type(4))) float f32x4;

union SV8 { bv8 v; bf16_t h[8]; };

__device__ __forceinline__ void gload_lds16(const void* g, void* l) {
  __builtin_amdgcn_global_load_lds(
      (const __attribute__((address_space(1))) unsigned int*)g,
      (__attribute__((address_space(3))) unsigned int*)l, 16, 0, 0);
}

// ---------- fp32 -> bf16 convert (exact grids; 8 elems/thread) ----------
__global__ __launch_bounds__(256) void cvt_kernel(const float* __restrict__ in,
                                                  bf16_t* __restrict__ out) {
  const size_t i = ((size_t)blockIdx.x * 256 + threadIdx.x) * 8;
  const f32x4 a = *(const f32x4*)(in + i);
  const f32x4 b = *(const f32x4*)(in + i + 4);
  SV8 o;
#pragma unroll
  for (int j = 0; j < 4; ++j) o.h[j] = __float2bfloat16(a[j]);
#pragma unroll
  for (int j = 0; j < 4; ++j) o.h[4 + j] = __float2bfloat16(b[j]);
  *(bv8*)(out + i) = o.v;
}

// ---------- 256x256-tile GEMM, C = A @ W^T (+bias, +opt elu+1) ----------
// A: [16384,1024] bf16. W: [N,1024] bf16 (N = 3072 merged QKV, or 1024).
// 512 threads = 8 waves (2M x 4N), per-wave C = 128x64. BK=32.
// LDS 128KB = 4 K-tile buffers x (A 16KB + B 16KB), fragment-order layout:
//   buffer byte fb*1024 + ks*256 + r*16 holds X[fb*16+r][ks*8..+7]  (conflict-free:
//   every wave-level ds_read_b128 and global_load_lds dest is a contiguous 1KB block).
// Counted-vmcnt pipeline: while computing K-tile t, stage tile t+3 into the buffer
// that held tile t-1 (reads of t-1 completed before the previous barrier).
// Closing "vmcnt(8); s_barrier" guarantees stages issued at iters <= t-2 (tile t+1)
// have landed, while the last 8 loads (tiles t+2, t+3) stay in flight. QKV=true:
// column group 0/1 get elu+1 -> bf16 to o0/o1, group 2 identity bf16 -> o2.
// QKV=false: identity fp32 -> o0.
template <bool QKV>
__global__ __launch_bounds__(512, 2) void gemm256(
    const bf16_t* __restrict__ A, const bf16_t* __restrict__ W,
    const float* __restrict__ b0, const float* __restrict__ b1,
    const float* __restrict__ b2, void* __restrict__ o0,
    void* __restrict__ o1, void* __restrict__ o2) {
  constexpr int K = 1024;
  constexpr int NT = QKV ? 12 : 4;     // N/256
  constexpr int NKT = K / 32;          // 32 K-tiles
  __shared__ char lds[131072];         // A: buf*16384; B: 65536 + buf*16384

  const int nwg = NT * 64;             // 768 or 256, %8 == 0
  const int wg = (blockIdx.x & 7) * (nwg >> 3) + (blockIdx.x >> 3);  // XCD swizzle
  const int m0 = (wg / NT) * 256;
  const int n0 = (wg % NT) * 256;
  const int t = threadIdx.x, l = t & 63, w = t >> 6;
  const int wm = w >> 2, wn = w & 3;   // wave grid 2(M) x 4(N)

  // staging maps: sweep j in {0,1}; slot s = j*512 + t
  const int s0r = (t >> 6) * 16 + (t & 15), s0c = ((t >> 4) & 3) * 8;
  const int s1 = 512 + t;
  const int s1r = (s1 >> 6) * 16 + (s1 & 15), s1c = ((s1 >> 4) & 3) * 8;
  const bf16_t* a0 = A + (size_t)(m0 + s0r) * K + s0c;
  const bf16_t* a1 = A + (size_t)(m0 + s1r) * K + s1c;
  const bf16_t* w0 = W + (size_t)(n0 + s0r) * K + s0c;
  const bf16_t* w1 = W + (size_t)(n0 + s1r) * K + s1c;
  char* la0 = lds + t * 16;
  char* la1 = lds + 8192 + t * 16;
  char* lb0 = lds + 65536 + t * 16;
  char* lb1 = lds + 65536 + 8192 + t * 16;

  f32x4 acc[8][4] = {};

  auto STAGE = [&](int tile, int q) {
    const size_t ko = (size_t)tile * 32;
    const int qo = q * 16384;
    gload_lds16(a0 + ko, la0 + qo);
    gload_lds16(w0 + ko, lb0 + qo);
    gload_lds16(a1 + ko, la1 + qo);
    gload_lds16(w1 + ko, lb1 + qo);
  };
  auto COMPUTE = [&](int q) {
    const char* ab = lds + q * 16384 + wm * 8192 + l * 16;
    const char* bb = lds + 65536 + q * 16384 + wn * 4096 + l * 16;
    bv8 af[8], bf[4];
#pragma unroll
    for (int m = 0; m < 8; ++m) af[m] = *(const bv8*)(ab + m * 1024);
#pragma unroll
    for (int n = 0; n < 4; ++n) bf[n] = *(const bv8*)(bb + n * 1024);
#pragma unroll
    for (int m = 0; m < 8; ++m)
#pragma unroll
      for (int n = 0; n < 4; ++n)
        acc[m][n] = __builtin_amdgcn_mfma_f32_16x16x32_bf16(af[m], bf[n],
                                                            acc[m][n], 0, 0, 0);
  };

  // prologue: stage tiles 0,1,2; wait tile 0 (all but last 8 insts)
  STAGE(0, 0);
  STAGE(1, 1);
  STAGE(2, 2);
  asm volatile("s_waitcnt vmcnt(8)" ::: "memory");
  __builtin_amdgcn_s_barrier();

  for (int kt = 0; kt < NKT - 3; ++kt) {       // kt = 0..28
    STAGE(kt + 3, (kt + 3) & 3);
    COMPUTE(kt & 3);
    asm volatile("s_waitcnt vmcnt(8)" ::: "memory");  // tile kt+1 landed
    __builtin_amdgcn_s_barrier();
  }
  // tails (no more staging): 29, 30, 31
  COMPUTE((NKT - 3) & 3);
  asm volatile("s_waitcnt vmcnt(4)" ::: "memory");
  __builtin_amdgcn_s_barrier();
  COMPUTE((NKT - 2) & 3);
  asm volatile("s_waitcnt vmcnt(0)" ::: "memory");
  __builtin_amdgcn_s_barrier();
  COMPUTE((NKT - 1) & 3);

  // epilogue. C/D: col = lane&15, row = (lane>>4)*4 + reg
  const int gq = n0 >> 10;  // 1024-col group (tiles are 256-aligned: uniform)
  const float* bias = QKV ? (gq == 0 ? b0 : (gq == 1 ? b1 : b2)) : b0;
  bf16_t* ob = (bf16_t*)(gq == 0 ? o0 : (gq == 1 ? o1 : o2));
  const int cb = (n0 & 1023) + wn * 64;
  const int rb = m0 + wm * 128 + ((l >> 4) << 2);
  const int cc = l & 15;
#pragma unroll
  for (int n = 0; n < 4; ++n) {
    const int col = cb + n * 16 + cc;
    const float bz = bias[col];
#pragma unroll
    for (int m = 0; m < 8; ++m) {
      const int row = rb + m * 16;
#pragma unroll
      for (int r = 0; r < 4; ++r) {
        float v = acc[m][n][r] + bz;
        if (QKV) {
          if (gq < 2) v = (v > 0.f) ? (v + 1.f) : __expf(v);  // elu(x)+1
          ob[(size_t)(row + r) * 1024 + col] = __float2bfloat16(v);
        } else {
          ((float*)o0)[(size_t)(row + r) * 1024 + col] = v;
        }
      }
    }
  }
}

// ---------- kv partial: pkv[chunk][bh][d][e] = sum_{s in chunk} k[s,d]*v[s,e] ----------
__global__ __launch_bounds__(256) void kv_partial(const bf16_t* __restrict__ Kmat,
                                                  const bf16_t* __restrict__ Vmat,
                                                  float* __restrict__ pkv) {
  const int chunk = blockIdx.x;   // 0..15
  const int bh = blockIdx.y;      // 0..63
  const int b = bh >> 4, h = bh & 15;
  const int t = threadIdx.x;
  __shared__ bf16_t kl[8][64], vl[8][64];
  float acc[16] = {};
  const int e = t & 63, d0 = (t >> 6) * 16;
  const int sl = t >> 5, c2 = (t & 31) * 2;
  const int s0 = chunk * (SEQ / KV_CHUNKS);
  const bf16_t* kp = Kmat + ((size_t)(b * SEQ + s0 + sl)) * EMB + h * 64 + c2;
  const bf16_t* vp = Vmat + ((size_t)(b * SEQ + s0 + sl)) * EMB + h * 64 + c2;
  for (int it = 0; it < (SEQ / KV_CHUNKS) / 8; ++it) {  // 32 iters of 8 rows
    const unsigned int kw = *(const unsigned int*)kp;
    const unsigned int vw = *(const unsigned int*)vp;
    __syncthreads();
    *(unsigned int*)&kl[sl][c2] = kw;
    *(unsigned int*)&vl[sl][c2] = vw;
    __syncthreads();
#pragma unroll
    for (int ss = 0; ss < 8; ++ss) {
      const float vv = __bfloat162float(vl[ss][e]);
      SV8 k0, k1;
      k0.v = *(const bv8*)&kl[ss][d0];
      k1.v = *(const bv8*)&kl[ss][d0 + 8];
#pragma unroll
      for (int dd = 0; dd < 8; ++dd) acc[dd] += __bfloat162float(k0.h[dd]) * vv;
#pragma unroll
      for (int dd = 0; dd < 8; ++dd) acc[8 + dd] += __bfloat162float(k1.h[dd]) * vv;
    }
    kp += 8 * EMB;
    vp += 8 * EMB;
  }
  float* outp = pkv + ((size_t)chunk * 64 + bh) * 4096;
#pragma unroll
  for (int dd = 0; dd < 16; ++dd) outp[(d0 + dd) * 64 + e] = acc[dd];
}

// ---------- kv reduce over chunks + transpose -> kvT[bh][e][d] (bf16) ----------
__global__ __launch_bounds__(256) void kv_reduce(const float* __restrict__ pkv,
                                                 bf16_t* __restrict__ kvT) {
  const int bh = blockIdx.x;
  const int t = threadIdx.x;
  __shared__ float tile[64][65];
#pragma unroll
  for (int ii = 0; ii < 16; ++ii) {
    const int idx = ii * 256 + t;  // d*64 + e
    float s = 0.f;
#pragma unroll
    for (int c = 0; c < KV_CHUNKS; ++c)
      s += pkv[((size_t)c * 64 + bh) * 4096 + idx];
    tile[idx >> 6][idx & 63] = s;
  }
  __syncthreads();
  bf16_t* outp = kvT + (size_t)bh * 4096;
#pragma unroll
  for (int ii = 0; ii < 16; ++ii) {
    const int o = ii * 256 + t;    // e*64 + d
    outp[o] = __float2bfloat16(tile[o & 63][o >> 6]);
  }
}

// ---------- ctx[s, h*64+e] = sum_d q[s, h*64+d] * kvT[bh][e][d]  (MFMA) ----------
__global__ __launch_bounds__(256, 4) void qkv_apply(const bf16_t* __restrict__ Q,
                                                    const bf16_t* __restrict__ kvT,
                                                    bf16_t* __restrict__ ctx) {
  __shared__ bf16_t Ql[128 * 64];  // frag order, fb = mb*2 + kt
  __shared__ bf16_t Bl[64 * 64];
  const int st = blockIdx.x;       // 0..31 (s-tile of 128)
  const int bh = blockIdx.y;       // 0..63
  const int b = bh >> 4, h = bh & 15;
  const int t = threadIdx.x, l = t & 63, w = t >> 6;

  const size_t qbase = ((size_t)(b * SEQ + st * 128)) * EMB + h * 64;
#pragma unroll
  for (int j = 0; j < 4; ++j) {
    const int vt = j * 256 + t;
    const int fb = vt >> 6;
    const int row = (fb >> 1) * 16 + (vt & 15);
    const int col = (fb & 1) * 32 + (((vt >> 4) & 3) << 3);
    gload_lds16(Q + qbase + (size_t)row * EMB + col, (char*)Ql + vt * 16);
  }
  const bf16_t* kvb = kvT + (size_t)bh * 4096;  // [64 e][64 d] row-major
#pragma unroll
  for (int j = 0; j < 2; ++j) {
    const int vt = j * 256 + t;
    const int fb = vt >> 6;
    const int row = (fb >> 1) * 16 + (vt & 15);
    const int col = (fb & 1) * 32 + (((vt >> 4) & 3) << 3);
    gload_lds16(kvb + row * 64 + col, (char*)Bl + vt * 16);
  }
  __syncthreads();

  f32x4 acc[2][4] = {};
#pragma unroll
  for (int kt = 0; kt < 2; ++kt) {
    bv8 a[2], bb[4];
#pragma unroll
    for (int i = 0; i < 2; ++i)
      a[i] = *(const bv8*)((const char*)Ql + (((w * 2 + i) * 2 + kt) * 1024) + l * 16);
#pragma unroll
    for (int j = 0; j < 4; ++j)
      bb[j] = *(const bv8*)((const char*)Bl + ((j * 2 + kt) * 1024) + l * 16);
#pragma unroll
    for (int i = 0; i < 2; ++i)
#pragma unroll
      for (int j = 0; j < 4; ++j)
        acc[i][j] = __builtin_amdgcn_mfma_f32_16x16x32_bf16(a[i], bb[j],
                                                            acc[i][j], 0, 0, 0);
  }

  const int cr = (l >> 4) << 2, cc = l & 15;
#pragma unroll
  for (int i = 0; i < 2; ++i)
#pragma unroll
    for (int j = 0; j < 4; ++j)
#pragma unroll
      for (int r = 0; r < 4; ++r) {
        const int row = st * 128 + w * 32 + i * 16 + cr + r;
        ctx[((size_t)(b * SEQ + row)) * EMB + h * 64 + j * 16 + cc] =
            __float2bfloat16(acc[i][j][r]);
      }
}

extern "C" void kernel_launch(void* const* d_in, const int* in_sizes, int n_in,
                              void* d_out, int out_size, void* d_ws, size_t ws_size,
                              hipStream_t stream) {
  (void)in_sizes; (void)n_in; (void)out_size;
  const float* x  = (const float*)d_in[0];
  const float* Wq = (const float*)d_in[1];
  const float* bq = (const float*)d_in[2];
  const float* Wk = (const float*)d_in[3];
  const float* bk = (const float*)d_in[4];
  const float* Wv = (const float*)d_in[5];
  const float* bv = (const float*)d_in[6];
  const float* Wo = (const float*)d_in[7];
  const float* bo = (const float*)d_in[8];

  // Workspace carve-up (~88.5 MB):
  //   xb 32MB | wqkv bf16 6MB (Wq|Wk|Wv rows 0..3071) | wob 2MB | vb 32MB
  //   | pkv 16MB | kvT 0.5MB.  ctx aliases xb. q,k live in d_out.
  const size_t NEED = 33554432ull + 4ull * 2097152ull + 33554432ull +
                      16777216ull + 524288ull;
  if (ws_size < NEED) return;

  char* p = (char*)d_ws;
  bf16_t* xb   = (bf16_t*)p;
  bf16_t* wqkv = (bf16_t*)(p + 33554432ull);                    // [3072,1024]
  bf16_t* wob  = (bf16_t*)(p + 33554432ull + 3ull * 2097152ull);
  bf16_t* vbuf = (bf16_t*)(p + 33554432ull + 4ull * 2097152ull);
  float*  pkv  = (float*)(p + 2ull * 33554432ull + 4ull * 2097152ull);
  bf16_t* kvT  = (bf16_t*)(p + 2ull * 33554432ull + 4ull * 2097152ull + 16777216ull);
  bf16_t* ctx  = xb;

  bf16_t* qb = (bf16_t*)d_out;
  bf16_t* kb = qb + (size_t)M_TOT * EMB;

  cvt_kernel<<<8192, 256, 0, stream>>>(x, xb);
  cvt_kernel<<<512, 256, 0, stream>>>(Wq, wqkv);                 // rows 0..1023
  cvt_kernel<<<512, 256, 0, stream>>>(Wk, wqkv + 1024 * 1024);   // rows 1024..2047
  cvt_kernel<<<512, 256, 0, stream>>>(Wv, wqkv + 2048 * 1024);   // rows 2048..3071
  cvt_kernel<<<512, 256, 0, stream>>>(Wo, wob);

  // merged QKV projection: q=elu+1->qb, k=elu+1->kb, v->vbuf
  gemm256<true><<<768, 512, 0, stream>>>(xb, wqkv, bq, bk, bv, qb, kb, vbuf);

  kv_partial<<<dim3(KV_CHUNKS, 64), 256, 0, stream>>>(kb, vbuf, pkv);
  kv_reduce<<<64, 256, 0, stream>>>(pkv, kvT);

  qkv_apply<<<dim3(32, 64), 256, 0, stream>>>(qb, kvT, ctx);

  // final projection -> fp32 d_out
  gemm256<false><<<256, 512, 0, stream>>>(ctx, wob, bo, nullptr, nullptr,
                                          d_out, nullptr, nullptr);
}

// Round 3
// 389.708 us; speedup vs baseline: 1.2705x; 1.0490x over previous
//
#include <hip/hip_runtime.h>
#include <hip/hip_bf16.h>
#include <cstdint>
#include <cstddef>

#define BATCH 4
#define SEQ   4096
#define EMB   1024
#define M_TOT (BATCH * SEQ)   // 16384
#define KV_CHUNKS 16

using bf16_t = __hip_bfloat16;
typedef __attribute__((ext_vector_type(8))) short bv8;    // 8 bf16 (4 VGPRs)
typedef __attribute__((ext_vector_type(4))) float f32x4;

union SV8 { bv8 v; bf16_t h[8]; };

__device__ __forceinline__ void gload_lds16(const void* g, void* l) {
  __builtin_amdgcn_global_load_lds(
      (const __attribute__((address_space(1))) unsigned int*)g,
      (__attribute__((address_space(3))) unsigned int*)l, 16, 0, 0);
}

#define BAR() asm volatile("s_barrier" ::: "memory")

// ---------- fp32 -> bf16 convert (8 elems/thread) ----------
__global__ __launch_bounds__(256) void cvt_kernel(const float* __restrict__ in,
                                                  bf16_t* __restrict__ out) {
  const size_t i = ((size_t)blockIdx.x * 256 + threadIdx.x) * 8;
  const f32x4 a = *(const f32x4*)(in + i);
  const f32x4 b = *(const f32x4*)(in + i + 4);
  SV8 o;
#pragma unroll
  for (int j = 0; j < 4; ++j) o.h[j] = __float2bfloat16(a[j]);
#pragma unroll
  for (int j = 0; j < 4; ++j) o.h[4 + j] = __float2bfloat16(b[j]);
  *(bv8*)(out + i) = o.v;
}

// 4 weight matrices (1M elems each) in one launch
__global__ __launch_bounds__(256) void wcvt_kernel(
    const float* __restrict__ s0, const float* __restrict__ s1,
    const float* __restrict__ s2, const float* __restrict__ s3,
    bf16_t* __restrict__ d0, bf16_t* __restrict__ d1,
    bf16_t* __restrict__ d2, bf16_t* __restrict__ d3) {
  const float* in; bf16_t* out;
  switch (blockIdx.y) {
    case 0:  in = s0; out = d0; break;
    case 1:  in = s1; out = d1; break;
    case 2:  in = s2; out = d2; break;
    default: in = s3; out = d3; break;
  }
  const size_t i = ((size_t)blockIdx.x * 256 + threadIdx.x) * 8;
  const f32x4 a = *(const f32x4*)(in + i);
  const f32x4 b = *(const f32x4*)(in + i + 4);
  SV8 o;
#pragma unroll
  for (int j = 0; j < 4; ++j) o.h[j] = __float2bfloat16(a[j]);
#pragma unroll
  for (int j = 0; j < 4; ++j) o.h[4 + j] = __float2bfloat16(b[j]);
  *(bv8*)(out + i) = o.v;
}

// ---------- 8-phase 256x256 GEMM, C = A @ W^T (+bias, +opt elu+1) ----------
// 512 thr = 8 waves (2M x 4N), per-wave C 128x64. BK=64, 16 K-tiles.
// LDS 128KB: A = dbuf*32768 + half*16384; B at +65536 same. Fragment-order
// halves (128 rows x 64 cols): byte = fb*2048 + ks*1024 + lane*16 holds
// X[fb*16 + (l&15)][ks*32 + (l>>4)*8 ..+8] -> every ds_read_b128 and
// global_load_lds dest is a contiguous per-wave 1KB block (conflict-free).
// Schedule (derived from the verified 8-phase template): per K-tile j,
// 4 quadrant phases; half (j,idx in B0,B1,A0,A1) staged at phase 4j-7+idx:
//   P1: read A-mh0(8) + B-all(8); stage A1(j+1);  bar; 16 MFMA (mh0 x nh0); bar
//   P2:                           stage B0(j+2);  bar; 16 MFMA (mh0 x nh1); bar
//   P3: read A-mh1(8);            stage B1(j+2);  bar; 16 MFMA (mh1 x nh1); bar
//   P4:                           stage A0(j+2);  vmcnt(6); bar; 16 MFMA (mh1 x nh0); bar
// Slot-overwrite safety: each slot's old data is last ds_read >=1 phase
// before the overwriting stage issues (B fully read at P1; A-half at P1/P3),
// and stage issue follows the prior phase's closing barrier. vmcnt(6) at P4
// leaves exactly the next K-tile's 3 newest halves in flight and guarantees
// K-tile j+1 resident at its P1.  VARIANT 0: QKV (N=3072; col-group 0/1
// elu+1 -> o0/o1, group 2 identity -> o2, all bf16). VARIANT 1: N=1024,
// per-batch W (= W + (m0>>12)*1M), fp32 out + bias.
template <int VARIANT>
__global__ __launch_bounds__(512, 2) void gemm8p(
    const bf16_t* __restrict__ A, const bf16_t* __restrict__ Wbase,
    const float* __restrict__ b0, const float* __restrict__ b1,
    const float* __restrict__ b2, void* __restrict__ o0,
    void* __restrict__ o1, void* __restrict__ o2) {
  constexpr int K = 1024;
  constexpr int NT = (VARIANT == 0) ? 12 : 4;
  constexpr int NKT = K / 64;          // 16
  __shared__ char lds[131072];

  const int nwg = NT * 64;             // 768 or 256, %8==0 (bijective swizzle)
  const int wg = (blockIdx.x & 7) * (nwg >> 3) + (blockIdx.x >> 3);
  const int m0 = (wg / NT) * 256;
  const int n0 = (wg % NT) * 256;
  const bf16_t* W = Wbase + (VARIANT ? (size_t)(m0 >> 12) * 1048576ull : 0);
  const int t = threadIdx.x, l = t & 63, w = t >> 6;
  const int wm = w >> 2, wn = w & 3;   // 2(M) x 4(N) wave grid

  // staging map: slot s in [0,1024) of a 16KB half; thread handles s=t, t+512
  const int sr = ((t >> 7) << 4) + (t & 15);                    // row 0..63
  const int sc = (((t >> 6) & 1) << 5) + (((t >> 4) & 3) << 3); // col
  const bf16_t* aRow = A + (size_t)(m0 + sr) * K + sc;
  const bf16_t* wRow = W + (size_t)(n0 + sr) * K + sc;
  char* dA = lds + t * 16;
  char* dB = lds + 65536 + t * 16;

  auto ST = [&](int isB, int hf, int kt) {   // stage one 16KB half-tile
    char* d = (isB ? dB : dA) + (kt & 1) * 32768 + hf * 16384;
    const bf16_t* s = (isB ? wRow : aRow) + (size_t)(hf * 128) * K + kt * 64;
    gload_lds16(s, d);
    gload_lds16(s + (size_t)64 * K, d + 8192);
  };

  const char* Ab = lds + wm * 16384 + l * 16;
  const char* Bb = lds + 65536 + (wn >> 1) * 16384 + (wn & 1) * 8192 + l * 16;

  f32x4 acc[8][4] = {};
  bv8 af[4][2], bf[4][2];

  // prologue: K0 complete + K1 B0,B1,A0 (7 halves); keep 3 newest in flight
  ST(1, 0, 0); ST(1, 1, 0); ST(0, 0, 0); ST(0, 1, 0);
  ST(1, 0, 1); ST(1, 1, 1); ST(0, 0, 1);
  asm volatile("s_waitcnt vmcnt(6)" ::: "memory");
  BAR();

#pragma unroll 1
  for (int j = 0; j < NKT; ++j) {
    const int db = (j & 1) * 32768;
    // ---- P1 ----
#pragma unroll
    for (int mb = 0; mb < 4; ++mb)
#pragma unroll
      for (int ks = 0; ks < 2; ++ks)
        af[mb][ks] = *(const bv8*)(Ab + db + mb * 2048 + ks * 1024);
#pragma unroll
    for (int nb = 0; nb < 4; ++nb)
#pragma unroll
      for (int ks = 0; ks < 2; ++ks)
        bf[nb][ks] = *(const bv8*)(Bb + db + nb * 2048 + ks * 1024);
    if (j + 1 < NKT) ST(0, 1, j + 1);
    BAR();
    __builtin_amdgcn_s_setprio(1);
#pragma unroll
    for (int mb = 0; mb < 4; ++mb)
#pragma unroll
      for (int nb = 0; nb < 2; ++nb)
#pragma unroll
        for (int ks = 0; ks < 2; ++ks)
          acc[mb][nb] = __builtin_amdgcn_mfma_f32_16x16x32_bf16(
              af[mb][ks], bf[nb][ks], acc[mb][nb], 0, 0, 0);
    __builtin_amdgcn_s_setprio(0);
    BAR();
    // ---- P2 ----
    if (j + 2 < NKT) ST(1, 0, j + 2);
    BAR();
    __builtin_amdgcn_s_setprio(1);
#pragma unroll
    for (int mb = 0; mb < 4; ++mb)
#pragma unroll
      for (int nb = 2; nb < 4; ++nb)
#pragma unroll
        for (int ks = 0; ks < 2; ++ks)
          acc[mb][nb] = __builtin_amdgcn_mfma_f32_16x16x32_bf16(
              af[mb][ks], bf[nb][ks], acc[mb][nb], 0, 0, 0);
    __builtin_amdgcn_s_setprio(0);
    BAR();
    // ---- P3 ----
#pragma unroll
    for (int mb = 0; mb < 4; ++mb)
#pragma unroll
      for (int ks = 0; ks < 2; ++ks)
        af[mb][ks] = *(const bv8*)(Ab + db + 8192 + mb * 2048 + ks * 1024);
    if (j + 2 < NKT) ST(1, 1, j + 2);
    BAR();
    __builtin_amdgcn_s_setprio(1);
#pragma unroll
    for (int mb = 0; mb < 4; ++mb)
#pragma unroll
      for (int nb = 2; nb < 4; ++nb)
#pragma unroll
        for (int ks = 0; ks < 2; ++ks)
          acc[4 + mb][nb] = __builtin_amdgcn_mfma_f32_16x16x32_bf16(
              af[mb][ks], bf[nb][ks], acc[4 + mb][nb], 0, 0, 0);
    __builtin_amdgcn_s_setprio(0);
    BAR();
    // ---- P4 ----
    if (j + 2 < NKT) {
      ST(0, 0, j + 2);
      asm volatile("s_waitcnt vmcnt(6)" ::: "memory");
    } else if (j == NKT - 2) {
      asm volatile("s_waitcnt vmcnt(0)" ::: "memory");
    }
    BAR();
    __builtin_amdgcn_s_setprio(1);
#pragma unroll
    for (int mb = 0; mb < 4; ++mb)
#pragma unroll
      for (int nb = 0; nb < 2; ++nb)
#pragma unroll
        for (int ks = 0; ks < 2; ++ks)
          acc[4 + mb][nb] = __builtin_amdgcn_mfma_f32_16x16x32_bf16(
              af[mb][ks], bf[nb][ks], acc[4 + mb][nb], 0, 0, 0);
    __builtin_amdgcn_s_setprio(0);
    BAR();
  }

  // epilogue. C/D: col = lane&15, row = (lane>>4)*4 + reg
  const int cr = (l >> 4) << 2, cc = l & 15;
  if (VARIANT == 0) {
    const int gq = n0 >> 10;  // 0=q, 1=k, 2=v (256-aligned tiles: uniform)
    const float* bias = gq == 0 ? b0 : (gq == 1 ? b1 : b2);
    bf16_t* ob = (bf16_t*)(gq == 0 ? o0 : (gq == 1 ? o1 : o2));
    const int cb = (n0 & 1023) + wn * 64;
#pragma unroll
    for (int nb = 0; nb < 4; ++nb) {
      const int col = cb + nb * 16 + cc;
      const float bz = bias[col];
#pragma unroll
      for (int mb = 0; mb < 8; ++mb) {
        const int row = m0 + wm * 128 + mb * 16 + cr;
#pragma unroll
        for (int r = 0; r < 4; ++r) {
          float v = acc[mb][nb][r] + bz;
          if (gq < 2) v = (v > 0.f) ? (v + 1.f) : __expf(v);  // elu(x)+1
          ob[(size_t)(row + r) * 1024 + col] = __float2bfloat16(v);
        }
      }
    }
  } else {
    const int cb = n0 + wn * 64;
#pragma unroll
    for (int nb = 0; nb < 4; ++nb) {
      const int col = cb + nb * 16 + cc;
      const float bz = b0[col];
#pragma unroll
      for (int mb = 0; mb < 8; ++mb) {
        const int row = m0 + wm * 128 + mb * 16 + cr;
#pragma unroll
        for (int r = 0; r < 4; ++r)
          ((float*)o0)[(size_t)(row + r) * 1024 + col] = acc[mb][nb][r] + bz;
      }
    }
  }
}

// ---------- kv partial: pkv[chunk][bh][d][e] = sum_{s in chunk} k[s,d]*v[s,e] ----------
__global__ __launch_bounds__(256) void kv_partial(const bf16_t* __restrict__ Kmat,
                                                  const bf16_t* __restrict__ Vmat,
                                                  float* __restrict__ pkv) {
  const int chunk = blockIdx.x;   // 0..15
  const int bh = blockIdx.y;      // 0..63
  const int b = bh >> 4, h = bh & 15;
  const int t = threadIdx.x;
  __shared__ bf16_t kl[8][64], vl[8][64];
  float acc[16] = {};
  const int e = t & 63, d0 = (t >> 6) * 16;
  const int sl = t >> 5, c2 = (t & 31) * 2;
  const int s0 = chunk * (SEQ / KV_CHUNKS);
  const bf16_t* kp = Kmat + ((size_t)(b * SEQ + s0 + sl)) * EMB + h * 64 + c2;
  const bf16_t* vp = Vmat + ((size_t)(b * SEQ + s0 + sl)) * EMB + h * 64 + c2;
  for (int it = 0; it < (SEQ / KV_CHUNKS) / 8; ++it) {
    const unsigned int kw = *(const unsigned int*)kp;
    const unsigned int vw = *(const unsigned int*)vp;
    __syncthreads();
    *(unsigned int*)&kl[sl][c2] = kw;
    *(unsigned int*)&vl[sl][c2] = vw;
    __syncthreads();
#pragma unroll
    for (int ss = 0; ss < 8; ++ss) {
      const float vv = __bfloat162float(vl[ss][e]);
      SV8 k0, k1;
      k0.v = *(const bv8*)&kl[ss][d0];
      k1.v = *(const bv8*)&kl[ss][d0 + 8];
#pragma unroll
      for (int dd = 0; dd < 8; ++dd) acc[dd] += __bfloat162float(k0.h[dd]) * vv;
#pragma unroll
      for (int dd = 0; dd < 8; ++dd) acc[8 + dd] += __bfloat162float(k1.h[dd]) * vv;
    }
    kp += 8 * EMB;
    vp += 8 * EMB;
  }
  float* outp = pkv + ((size_t)chunk * 64 + bh) * 4096;
#pragma unroll
  for (int dd = 0; dd < 16; ++dd) outp[(d0 + dd) * 64 + e] = acc[dd];
}

// ---------- kv reduce over chunks -> kvf[bh][d][e] bf16 ----------
__global__ __launch_bounds__(256) void kv_reduce(const float* __restrict__ pkv,
                                                 bf16_t* __restrict__ kvf) {
  const int bh = blockIdx.x;
  const int t = threadIdx.x;
#pragma unroll
  for (int ii = 0; ii < 16; ++ii) {
    const int idx = ii * 256 + t;  // d*64 + e
    float s = 0.f;
#pragma unroll
    for (int c = 0; c < KV_CHUNKS; ++c)
      s += pkv[((size_t)c * 64 + bh) * 4096 + idx];
    kvf[(size_t)bh * 4096 + idx] = __float2bfloat16(s);
  }
}

// ---------- fold: MT[b][f, h*64+d] = sum_e Wo[f, h*64+e] * kvf[bh][d][e] ----------
// Per block: 128 f-rows x 64 d for one (b,h). M=f, N=d, K=e=64.
__global__ __launch_bounds__(256) void fold_kernel(const bf16_t* __restrict__ Wo,
                                                   const bf16_t* __restrict__ kvf,
                                                   bf16_t* __restrict__ MT) {
  __shared__ char lds[24576];   // A 16KB | B 8KB
  const int ft = blockIdx.x;    // 0..7
  const int bh = blockIdx.y;    // 0..63
  const int b = bh >> 4, h = bh & 15;
  const int t = threadIdx.x, l = t & 63, w = t >> 6;
#pragma unroll
  for (int q = 0; q < 4; ++q) {
    const int s = q * 256 + t;
    const int row = ((s >> 7) << 4) + (s & 15);
    const int col = (((s >> 6) & 1) << 5) + (((s >> 4) & 3) << 3);
    gload_lds16(Wo + (size_t)(ft * 128 + row) * 1024 + h * 64 + col, lds + s * 16);
  }
#pragma unroll
  for (int q = 0; q < 2; ++q) {
    const int s = q * 256 + t;
    const int row = ((s >> 7) << 4) + (s & 15);
    const int col = (((s >> 6) & 1) << 5) + (((s >> 4) & 3) << 3);
    gload_lds16(kvf + (size_t)bh * 4096 + row * 64 + col, lds + 16384 + s * 16);
  }
  asm volatile("s_waitcnt vmcnt(0)" ::: "memory");
  BAR();
  f32x4 acc[2][4] = {};
#pragma unroll
  for (int ks = 0; ks < 2; ++ks) {
    bv8 am[2], bn[4];
#pragma unroll
    for (int i = 0; i < 2; ++i)
      am[i] = *(const bv8*)(lds + (w * 2 + i) * 2048 + ks * 1024 + l * 16);
#pragma unroll
    for (int nb = 0; nb < 4; ++nb)
      bn[nb] = *(const bv8*)(lds + 16384 + nb * 2048 + ks * 1024 + l * 16);
#pragma unroll
    for (int i = 0; i < 2; ++i)
#pragma unroll
      for (int nb = 0; nb < 4; ++nb)
        acc[i][nb] = __builtin_amdgcn_mfma_f32_16x16x32_bf16(am[i], bn[nb],
                                                             acc[i][nb], 0, 0, 0);
  }
  bf16_t* out = MT + (size_t)b * 1048576ull;
  const int cr = (l >> 4) << 2, cc = l & 15;
#pragma unroll
  for (int i = 0; i < 2; ++i)
#pragma unroll
    for (int nb = 0; nb < 4; ++nb)
#pragma unroll
      for (int r = 0; r < 4; ++r)
        out[(size_t)(ft * 128 + w * 32 + i * 16 + cr + r) * 1024 + h * 64 +
            nb * 16 + cc] = __float2bfloat16(acc[i][nb][r]);
}

extern "C" void kernel_launch(void* const* d_in, const int* in_sizes, int n_in,
                              void* d_out, int out_size, void* d_ws, size_t ws_size,
                              hipStream_t stream) {
  (void)in_sizes; (void)n_in; (void)out_size;
  const float* x  = (const float*)d_in[0];
  const float* Wq = (const float*)d_in[1];
  const float* bq = (const float*)d_in[2];
  const float* Wk = (const float*)d_in[3];
  const float* bk = (const float*)d_in[4];
  const float* Wv = (const float*)d_in[5];
  const float* bv = (const float*)d_in[6];
  const float* Wo = (const float*)d_in[7];
  const float* bo = (const float*)d_in[8];

  // ws (72MB peak): [0,32M) xb, later reused as pkv(16M)|kvf(@16M,0.5M)|MT(@17M,8M)
  //                 [32M,38M) wqkv | [38M,40M) wob | [40M,72M) q
  // d_out (64MB): k at [0,32M), v at [32M,64M) during the middle phase; both
  // dead before the final gemm overwrites d_out with fp32 results.
  const size_t NEED = 72ull * 1024 * 1024;
  if (ws_size < NEED) return;

  char* p = (char*)d_ws;
  bf16_t* xb   = (bf16_t*)p;
  float*  pkv  = (float*)p;                         // aliases xb (x dead)
  bf16_t* kvf  = (bf16_t*)(p + 16777216ull);
  bf16_t* MT   = (bf16_t*)(p + 17825792ull);        // 4 x [1024,1024] bf16
  bf16_t* wqkv = (bf16_t*)(p + 33554432ull);        // [3072,1024]
  bf16_t* wob  = (bf16_t*)(p + 39845888ull);
  bf16_t* qb   = (bf16_t*)(p + 41943040ull);

  bf16_t* kb = (bf16_t*)d_out;
  bf16_t* vb = kb + 16777216ull;

  cvt_kernel<<<8192, 256, 0, stream>>>(x, xb);
  wcvt_kernel<<<dim3(512, 4), 256, 0, stream>>>(
      Wq, Wk, Wv, Wo, wqkv, wqkv + 1048576, wqkv + 2097152, wob);

  // merged QKV projection: q=elu+1 -> qb(ws), k=elu+1 -> kb(d_out), v -> vb(d_out)
  gemm8p<0><<<768, 512, 0, stream>>>(xb, wqkv, bq, bk, bv, qb, kb, vb);

  kv_partial<<<dim3(KV_CHUNKS, 64), 256, 0, stream>>>(kb, vb, pkv);
  kv_reduce<<<64, 256, 0, stream>>>(pkv, kvf);
  fold_kernel<<<dim3(8, 64), 256, 0, stream>>>(wob, kvf, MT);

  // out = q @ MT[b]^T + bo  (fp32 d_out)
  gemm8p<1><<<256, 512, 0, stream>>>(qb, MT, bo, nullptr, nullptr,
                                     d_out, nullptr, nullptr);
}